// Round 15
// baseline (258.038 us; speedup 1.0000x reference)
//
#include <hip/hip_runtime.h>
#include <hip/hip_bf16.h>

#define D 128
#define LOG2E 1.4426950408889634f

typedef __attribute__((ext_vector_type(8))) short bf16x8;
typedef __attribute__((ext_vector_type(4))) float f32x4;

__device__ __forceinline__ unsigned short f2bf_bits(float f) {
    union { __hip_bfloat16 h; unsigned short u; } c;
    c.h = __float2bfloat16(f);
    return c.u;
}
__device__ __forceinline__ float bfbits2f(unsigned short u) {
    return __uint_as_float(((unsigned)u) << 16);
}
__device__ __forceinline__ float ldf(const void* p, size_t i, int f32) {
    return f32 ? ((const float*)p)[i] : bfbits2f(((const unsigned short*)p)[i]);
}
__device__ __forceinline__ void unpk(unsigned u, float& a, float& b) {
    a = __uint_as_float(u << 16);
    b = __uint_as_float(u & 0xFFFF0000u);
}

// ---- K1: prep = dtype-detect (per-block local) + wq (transposed write)
//         + trans of 5 raw weights + count (rank captured for free).
// wT job map: 0 Wsq_s 1 W_s 2 Wsq_d 3 W_d 4 loopW 5 evoW 6 Wsq_r 7 W_r
__global__ __launch_bounds__(256) void prep_kernel(
    const void* __restrict__ node, const void* __restrict__ wtrip,
    const void* __restrict__ wquad, const void* __restrict__ loopW,
    const void* __restrict__ evoW, unsigned short* __restrict__ wT,
    int* __restrict__ cnt, int* __restrict__ rank,
    const int* __restrict__ dst, int* __restrict__ flag, int E) {
    __shared__ int sflag;
    int tid = threadIdx.x;
    int bad = 0;
    if (tid < 64) {
        for (int j = 0; j < 4; j++) {
            float v = bfbits2f(((const unsigned short*)node)[tid + 64 * j]);
            if (!(fabsf(v) < 1e4f)) bad = 1;
        }
    }
    unsigned long long m = __ballot(bad);
    if (tid == 0) sflag = (m != 0ull) ? 1 : 0;
    __syncthreads();
    int f32 = sflag;
    int bx = blockIdx.x;
    if (bx == 0 && tid == 0) *flag = f32;

    if (bx < 192) {
        int unit = bx * 2 + (tid >> 7);
        int k = unit & 127, mjob = unit >> 7;
        int t = tid & 127;
        float acc = 0.f;
        for (int j = 0; j < D; j++)
            acc += ldf(wtrip, (size_t)mjob * D * D + (size_t)k * D + j, f32) *
                   ldf(wquad, (size_t)j * D + t, f32);
        const int jmap0 = (mjob == 0) ? 0 : (mjob == 1 ? 6 : 2);
        wT[(size_t)jmap0 * D * D + (size_t)t * D + k] = f2bf_bits(acc);
    } else if (bx < 272) {
        int u = bx - 192;   // [0,80): 5 jobs x 16 segments
        int jr = u >> 4, seg = u & 15;
        const void* srcp; size_t base; int j;
        switch (jr) {
            case 0: srcp = wtrip; base = 0;             j = 1; break;
            case 1: srcp = wtrip; base = 2 * D * D;     j = 3; break;
            case 2: srcp = loopW; base = 0;             j = 4; break;
            case 3: srcp = evoW;  base = 0;             j = 5; break;
            default: srcp = wtrip; base = (size_t)D * D; j = 7; break;
        }
        for (int c = tid; c < 1024; c += 256) {
            int idx = seg * 1024 + c;
            int n = idx >> 7, k = idx & 127;
            unsigned short b = f32 ? f2bf_bits(((const float*)srcp)[base + (size_t)k * D + n])
                                   : ((const unsigned short*)srcp)[base + (size_t)k * D + n];
            wT[(size_t)j * D * D + (size_t)n * D + k] = b;
        }
    } else {
        int e = (bx - 272) * 256 + tid;
        if (e < E) rank[e] = atomicAdd(&cnt[dst[e]], 1);
    }
}

// ---- K2: fused exclusive scan: local 256-scan + self-computed carry ----
__global__ void scan_kernel(const int* __restrict__ cnt, int* __restrict__ offs,
                            int N, int E) {
    __shared__ int sh[256];
    int tid = threadIdx.x, b = blockIdx.x;
    int base = b * 256;
    int i = base + tid;
    int v = (i < N) ? cnt[i] : 0;
    sh[tid] = v;
    __syncthreads();
    for (int o = 1; o < 256; o <<= 1) {
        int t = (tid >= o) ? sh[tid - o] : 0;
        __syncthreads();
        sh[tid] += t;
        __syncthreads();
    }
    int local = sh[tid] - v;
    __syncthreads();
    int part = 0;
    for (int j = tid; j < base; j += 256) part += cnt[j];
    sh[tid] = part;
    __syncthreads();
    for (int o = 128; o; o >>= 1) {
        if (tid < o) sh[tid] += sh[tid + o];
        __syncthreads();
    }
    int carry = sh[0];
    if (i < N) offs[i] = local + carry;
    if (b == 0 && tid == 0) offs[N] = E;
}

// ---- K3: table GEMM, 512-thread blocks (R14-proven) + rank scatter ----
__global__ __launch_bounds__(512) void gemm_kernel(
    const void* __restrict__ node, const void* __restrict__ rel,
    const unsigned short* __restrict__ wT, const int* __restrict__ cnt,
    unsigned* __restrict__ nodeST, unsigned* __restrict__ nodeDT,
    unsigned* __restrict__ relRT, unsigned* __restrict__ loopSel,
    const int* __restrict__ flag, int N, int R, int nodeBlocks,
    const int* __restrict__ src, const int* __restrict__ dst,
    const int* __restrict__ et, const int* __restrict__ offs,
    const int* __restrict__ rank, unsigned* __restrict__ ePack, int E) {
    __shared__ __align__(16) unsigned short Wt[D][D + 8];

    int bx = blockIdx.x, by = blockIdx.y;
    int tid = threadIdx.y * 64 + threadIdx.x;
    int isRel = 0, jp;
    if (bx >= nodeBlocks) {
        if (by == 1) {  // scatter range: pure (no atomics)
            int e = (bx - nodeBlocks) * 512 + tid;
            if (e < E) {
                int d = dst[e];
                ePack[offs[d] + rank[e]] = (unsigned)src[e] | ((unsigned)et[e] << 20);
            }
            return;
        }
        if (by != 0 || bx - nodeBlocks >= (R + 127) / 128) return;
        isRel = 1;
        jp = 3;
    } else {
        jp = by;
    }

    int f32 = *flag;
    int rows = isRel ? R : N;
    int row0 = (isRel ? bx - nodeBlocks : bx) * 128;
    const void* A = isRel ? rel : node;

    int lane = threadIdx.x, wv = threadIdx.y;  // wv in [0,8)
    int l16 = lane & 15, quad = lane >> 4;
    int ar = row0 + wv * 16 + l16;
    int ar_c = ar < rows ? ar : rows - 1;

    int qIdx, tIdx;
    unsigned* O = nullptr;
    switch (jp) {
        case 0: qIdx = 0; tIdx = 1; O = nodeST; break;
        case 1: qIdx = 2; tIdx = 3; O = nodeDT; break;
        case 2: qIdx = 4; tIdx = 5; break;  // loopW/evoW pair
        default: qIdx = 6; tIdx = 7; O = relRT; break;
    }

    bf16x8 af[4];
#pragma unroll
    for (int kk = 0; kk < 4; kk++) {
        int k = kk * 32 + quad * 8;
        if (f32) {
            const float* Af = (const float*)A + (size_t)ar_c * D + k;
#pragma unroll
            for (int j = 0; j < 8; j++) af[kk][j] = (short)f2bf_bits(Af[j]);
        } else {
            af[kk] = *(const bf16x8*)((const unsigned short*)A + (size_t)ar_c * D + k);
        }
    }

    const unsigned short* gQ = wT + (size_t)qIdx * D * D;
    const unsigned short* gT = wT + (size_t)tIdx * D * D;

    bf16x8 wreg[4], wreg2[4];
#pragma unroll
    for (int i = 0; i < 4; i++) {
        int c = tid + i * 512;
        wreg[i] = *(const bf16x8*)(gQ + (c >> 4) * 128 + (c & 15) * 8);
    }

    f32x4 accQ[8], accT[8];
#pragma unroll
    for (int i = 0; i < 8; i++) {
        accQ[i] = (f32x4){0.f, 0.f, 0.f, 0.f};
        accT[i] = (f32x4){0.f, 0.f, 0.f, 0.f};
    }

    for (int pass = 0; pass < 2; pass++) {
#pragma unroll
        for (int i = 0; i < 4; i++) {
            int c = tid + i * 512;
            *(bf16x8*)(&Wt[c >> 4][(c & 15) * 8]) = wreg[i];
        }
        if (pass == 0) {
#pragma unroll
            for (int i = 0; i < 4; i++) {
                int c = tid + i * 512;
                wreg2[i] = *(const bf16x8*)(gT + (c >> 4) * 128 + (c & 15) * 8);
            }
        }
        __syncthreads();
        f32x4* acc = pass ? accT : accQ;
#pragma unroll
        for (int kk = 0; kk < 4; kk++) {
#pragma unroll
            for (int nt = 0; nt < 8; nt++) {
                bf16x8 bfr = *(const bf16x8*)(&Wt[nt * 16 + l16][kk * 32 + quad * 8]);
                acc[nt] = __builtin_amdgcn_mfma_f32_16x16x32_bf16(af[kk], bfr, acc[nt], 0, 0, 0);
            }
        }
        __syncthreads();
#pragma unroll
        for (int i = 0; i < 4; i++) wreg[i] = wreg2[i];
    }

    int cr0 = row0 + wv * 16 + quad * 4;
    int odd = l16 & 1;
    if (jp != 2) {
#pragma unroll
        for (int r = 0; r < 4; r++) {
            int cr = cr0 + r;
#pragma unroll
            for (int nt = 0; nt < 8; nt++) {
                float vQ = accQ[nt][r] * LOG2E;  // pre-scale logits for exp2
                float vT = accT[nt][r];
                float oQ = __shfl_xor(vQ, 1);
                float oT = __shfl_xor(vT, 1);
                unsigned w;
                if (!odd) w = (unsigned)f2bf_bits(vQ) | ((unsigned)f2bf_bits(oQ) << 16);
                else      w = (unsigned)f2bf_bits(oT) | ((unsigned)f2bf_bits(vT) << 16);
                if (cr < rows) O[(size_t)cr * 128 + nt * 16 + l16] = w;
            }
        }
    } else {
#pragma unroll
        for (int r = 0; r < 4; r++) {
            int cr = cr0 + r;
            int deg = (cr < rows) ? cnt[cr] : 0;
#pragma unroll
            for (int nt = 0; nt < 8; nt++) {
                float vL = accQ[nt][r], vE = accT[nt][r];
                float oL = __shfl_xor(vL, 1);
                float oE = __shfl_xor(vE, 1);
                unsigned wl, we;
                if (!odd) {
                    wl = (unsigned)f2bf_bits(vL) | ((unsigned)f2bf_bits(oL) << 16);
                    we = (unsigned)f2bf_bits(vE) | ((unsigned)f2bf_bits(oE) << 16);
                } else {
                    wl = (unsigned)f2bf_bits(oL) | ((unsigned)f2bf_bits(vL) << 16);
                    we = (unsigned)f2bf_bits(oE) | ((unsigned)f2bf_bits(vE) << 16);
                }
                if (cr < rows && !odd)
                    loopSel[(size_t)cr * 64 + nt * 8 + (l16 >> 1)] = (deg > 0) ? wl : we;
            }
        }
    }
}

// ---- K4: wave-per-node aggregation + layernorm.
// Batched gathers into explicit arrays (loads in flight before math),
// masked tail batch (no latency-serial singles), 32-bit voffset indexing,
// leaky = max(q, 0.01q), td folded out of the loop (h = h' + td*den).
__global__ __launch_bounds__(256, 4) void agg_kernel(
    const int* __restrict__ offs, const unsigned* __restrict__ ePack,
    const uint2* __restrict__ ST, const uint2* __restrict__ RT,
    const uint2* __restrict__ DT, const unsigned* __restrict__ loopSel,
    const void* __restrict__ normv, void* __restrict__ out,
    const int* __restrict__ flag, int N) {
    int n = blockIdx.x * 4 + threadIdx.y;
    if (n >= N) return;
    int f32 = *flag;
    int lane = threadIdx.x;
    int start = offs[n], end = offs[n + 1];
    int deg = end - start;

    unsigned ul = loopSel[(unsigned)n * 64u + lane];
    uint2 ud = DT[(unsigned)n * 64u + lane];
    float qd0, qd1, td0, td1, acc0, acc1;
    unpk(ud.x, qd0, qd1);
    unpk(ud.y, td0, td1);
    unpk(ul, acc0, acc1);

    float den0 = 0.f, den1 = 0.f, h0 = 0.f, h1 = 0.f;
#define EMATH(US, UR, MSK)                                            \
    {                                                                 \
        float qs0, qs1, qr0, qr1, ts0, ts1, tr0, tr1;                 \
        unpk(US.x, qs0, qs1); unpk(UR.x, qr0, qr1);                   \
        unpk(US.y, ts0, ts1); unpk(UR.y, tr0, tr1);                   \
        float q0 = qs0 + qr0 + qd0, q1 = qs1 + qr1 + qd1;             \
        float a0 = fmaxf(q0, 0.01f * q0);                             \
        float a1 = fmaxf(q1, 0.01f * q1);                             \
        float ex0 = exp2f(a0) * (MSK), ex1 = exp2f(a1) * (MSK);       \
        den0 += ex0; den1 += ex1;                                     \
        h0 += ex0 * (ts0 + tr0);                                      \
        h1 += ex1 * (ts1 + tr1);                                      \
    }
    int e = start;
    for (; e + 3 < end; e += 4) {
        uint2 us[4], ur[4];
#pragma unroll
        for (int j = 0; j < 4; j++) {
            unsigned pk = ePack[e + j];
            us[j] = ST[((pk & 0xFFFFFu) << 6) | (unsigned)lane];
            ur[j] = RT[((pk >> 20) << 6) | (unsigned)lane];
        }
#pragma unroll
        for (int j = 0; j < 4; j++) EMATH(us[j], ur[j], 1.0f)
    }
    if (e < end) {  // masked tail batch: 1-3 real edges, gathers still wide
        uint2 us[4], ur[4];
        float mk[4];
#pragma unroll
        for (int j = 0; j < 4; j++) {
            int ej = e + j < end ? e + j : end - 1;
            mk[j] = (e + j < end) ? 1.0f : 0.0f;
            unsigned pk = ePack[ej];
            us[j] = ST[((pk & 0xFFFFFu) << 6) | (unsigned)lane];
            ur[j] = RT[((pk >> 20) << 6) | (unsigned)lane];
        }
#pragma unroll
        for (int j = 0; j < 4; j++) EMATH(us[j], ur[j], mk[j])
    }

    float x0, x1;
    if (deg > 0) {
        float nrm = ldf(normv, n, f32);
        x0 = (h0 / den0 + td0) * nrm + acc0;  // td folded back via h'+td*den
        x1 = (h1 / den1 + td1) * nrm + acc1;
    } else {
        x0 = acc0;
        x1 = acc1;
    }

    float s = x0 + x1, ss = x0 * x0 + x1 * x1;
#pragma unroll
    for (int o = 32; o; o >>= 1) {
        s += __shfl_xor(s, o);
        ss += __shfl_xor(ss, o);
    }
    float mu = s * (1.f / 128.f);
    float var = ss * (1.f / 128.f) - mu * mu;
    float rstd = rsqrtf(var + 1e-5f);
    float y0 = (x0 - mu) * rstd, y1 = (x1 - mu) * rstd;

    if (f32) {
        ((float2*)out)[(unsigned)n * 64u + lane] = make_float2(y0, y1);
    } else {
        unsigned ob = (unsigned)f2bf_bits(y0) | ((unsigned)f2bf_bits(y1) << 16);
        ((unsigned*)out)[(unsigned)n * 64u + lane] = ob;
    }
}

extern "C" void kernel_launch(void* const* d_in, const int* in_sizes, int n_in,
                              void* d_out, int out_size, void* d_ws, size_t ws_size,
                              hipStream_t stream) {
    const void* node = d_in[0];
    const void* rel = d_in[1];
    const void* normv = d_in[2];
    const void* wtrip = d_in[3];
    const void* wquad = d_in[4];
    const void* loopW = d_in[5];
    const void* evoW = d_in[6];
    const int* src = (const int*)d_in[7];
    const int* dst = (const int*)d_in[8];
    const int* et = (const int*)d_in[9];

    int N = in_sizes[0] / D;
    int R = in_sizes[1] / D;
    int E = in_sizes[7];
    int nb = (N + 255) / 256;
    int nodeBlocks = (N + 127) / 128;
    int relBlocks = (R + 127) / 128;
    int scatBlocks = (E + 511) / 512;

    char* p = (char*)d_ws;
    auto alloc = [&](size_t bytes) -> void* {
        void* r = (void*)p;
        p += (bytes + 255) & ~(size_t)255;
        return r;
    };
    unsigned* nodeST = (unsigned*)alloc((size_t)N * 128 * 4);
    unsigned* nodeDT = (unsigned*)alloc((size_t)N * 128 * 4);
    unsigned* relRT = (unsigned*)alloc((size_t)R * 128 * 4);
    unsigned* loopSel = (unsigned*)alloc((size_t)N * 64 * 4);
    unsigned short* wT = (unsigned short*)alloc((size_t)8 * D * D * 2);
    int* cnt = (int*)alloc((size_t)N * 4);
    int* offs = (int*)alloc((size_t)(N + 1) * 4);
    int* rank = (int*)alloc((size_t)E * 4);
    unsigned* ePack = (unsigned*)alloc((size_t)E * 4);
    int* flag = (int*)alloc(4);

    hipMemsetAsync(cnt, 0, (size_t)N * 4, stream);
    prep_kernel<<<272 + (E + 255) / 256, 256, 0, stream>>>(
        node, wtrip, wquad, loopW, evoW, wT, cnt, rank, dst, flag, E);
    scan_kernel<<<nb, 256, 0, stream>>>(cnt, offs, N, E);
    int xext = nodeBlocks + (scatBlocks > relBlocks ? scatBlocks : relBlocks);
    gemm_kernel<<<dim3(xext, 3), dim3(64, 8), 0, stream>>>(
        node, rel, wT, cnt, nodeST, nodeDT, relRT, loopSel, flag, N, R, nodeBlocks,
        src, dst, et, offs, rank, ePack, E);
    agg_kernel<<<(N + 3) / 4, dim3(64, 4), 0, stream>>>(
        offs, ePack, (const uint2*)nodeST, (const uint2*)relRT, (const uint2*)nodeDT,
        loopSel, normv, d_out, flag, N);
}

// Round 16
// 247.656 us; speedup vs baseline: 1.0419x; 1.0419x over previous
//
#include <hip/hip_runtime.h>
#include <hip/hip_bf16.h>

#define D 128
#define LOG2E 1.4426950408889634f

typedef __attribute__((ext_vector_type(8))) short bf16x8;
typedef __attribute__((ext_vector_type(4))) float f32x4;

__device__ __forceinline__ unsigned short f2bf_bits(float f) {
    union { __hip_bfloat16 h; unsigned short u; } c;
    c.h = __float2bfloat16(f);
    return c.u;
}
__device__ __forceinline__ float bfbits2f(unsigned short u) {
    return __uint_as_float(((unsigned)u) << 16);
}
__device__ __forceinline__ float ldf(const void* p, size_t i, int f32) {
    return f32 ? ((const float*)p)[i] : bfbits2f(((const unsigned short*)p)[i]);
}
__device__ __forceinline__ void unpk(unsigned u, float& a, float& b) {
    a = __uint_as_float(u << 16);
    b = __uint_as_float(u & 0xFFFF0000u);
}

// ---- K1: prep = dtype-detect (per-block local) + wq (transposed write)
//         + trans of 5 raw weights + count (rank captured for free).
// wT job map: 0 Wsq_s 1 W_s 2 Wsq_d 3 W_d 4 loopW 5 evoW 6 Wsq_r 7 W_r
__global__ __launch_bounds__(256) void prep_kernel(
    const void* __restrict__ node, const void* __restrict__ wtrip,
    const void* __restrict__ wquad, const void* __restrict__ loopW,
    const void* __restrict__ evoW, unsigned short* __restrict__ wT,
    int* __restrict__ cnt, int* __restrict__ rank,
    const int* __restrict__ dst, int* __restrict__ flag, int E) {
    __shared__ int sflag;
    int tid = threadIdx.x;
    int bad = 0;
    if (tid < 64) {
        for (int j = 0; j < 4; j++) {
            float v = bfbits2f(((const unsigned short*)node)[tid + 64 * j]);
            if (!(fabsf(v) < 1e4f)) bad = 1;
        }
    }
    unsigned long long m = __ballot(bad);
    if (tid == 0) sflag = (m != 0ull) ? 1 : 0;
    __syncthreads();
    int f32 = sflag;
    int bx = blockIdx.x;
    if (bx == 0 && tid == 0) *flag = f32;

    if (bx < 192) {
        int unit = bx * 2 + (tid >> 7);
        int k = unit & 127, mjob = unit >> 7;
        int t = tid & 127;
        float acc = 0.f;
        for (int j = 0; j < D; j++)
            acc += ldf(wtrip, (size_t)mjob * D * D + (size_t)k * D + j, f32) *
                   ldf(wquad, (size_t)j * D + t, f32);
        const int jmap0 = (mjob == 0) ? 0 : (mjob == 1 ? 6 : 2);
        wT[(size_t)jmap0 * D * D + (size_t)t * D + k] = f2bf_bits(acc);
    } else if (bx < 272) {
        int u = bx - 192;   // [0,80): 5 jobs x 16 segments
        int jr = u >> 4, seg = u & 15;
        const void* srcp; size_t base; int j;
        switch (jr) {
            case 0: srcp = wtrip; base = 0;             j = 1; break;
            case 1: srcp = wtrip; base = 2 * D * D;     j = 3; break;
            case 2: srcp = loopW; base = 0;             j = 4; break;
            case 3: srcp = evoW;  base = 0;             j = 5; break;
            default: srcp = wtrip; base = (size_t)D * D; j = 7; break;
        }
        for (int c = tid; c < 1024; c += 256) {
            int idx = seg * 1024 + c;
            int n = idx >> 7, k = idx & 127;
            unsigned short b = f32 ? f2bf_bits(((const float*)srcp)[base + (size_t)k * D + n])
                                   : ((const unsigned short*)srcp)[base + (size_t)k * D + n];
            wT[(size_t)j * D * D + (size_t)n * D + k] = b;
        }
    } else {
        int e = (bx - 272) * 256 + tid;
        if (e < E) rank[e] = atomicAdd(&cnt[dst[e]], 1);
    }
}

// ---- K2: per-block exclusive scan, block totals to part (R14-proven) ----
__global__ void scan_block(const int* __restrict__ cnt, int* __restrict__ offs,
                           int* __restrict__ part, int N) {
    __shared__ int sh[256];
    int tid = threadIdx.x;
    int i = blockIdx.x * 256 + tid;
    int v = (i < N) ? cnt[i] : 0;
    sh[tid] = v;
    __syncthreads();
    for (int o = 1; o < 256; o <<= 1) {
        int t = (tid >= o) ? sh[tid - o] : 0;
        __syncthreads();
        sh[tid] += t;
        __syncthreads();
    }
    if (i < N) offs[i] = sh[tid] - v;
    if (tid == 255) part[blockIdx.x] = sh[255];
}

// ---- K3: each block reduces part[0..b) itself, adds carry (nb<=256) ----
__global__ void scan_fix(int* __restrict__ offs, const int* __restrict__ part,
                         int N, int E) {
    __shared__ int sh[256];
    int tid = threadIdx.x, b = blockIdx.x;
    sh[tid] = (tid < b) ? part[tid] : 0;
    __syncthreads();
    for (int o = 128; o; o >>= 1) {
        if (tid < o) sh[tid] += sh[tid + o];
        __syncthreads();
    }
    int carry = sh[0];
    int i = b * 256 + tid;
    if (i < N) offs[i] += carry;
    if (b == 0 && tid == 0) offs[N] = E;
}

// ---- K4: table GEMM, 512-thread blocks (R14-proven) + rank scatter ----
__global__ __launch_bounds__(512) void gemm_kernel(
    const void* __restrict__ node, const void* __restrict__ rel,
    const unsigned short* __restrict__ wT, const int* __restrict__ cnt,
    unsigned* __restrict__ nodeST, unsigned* __restrict__ nodeDT,
    unsigned* __restrict__ relRT, unsigned* __restrict__ loopSel,
    const int* __restrict__ flag, int N, int R, int nodeBlocks,
    const int* __restrict__ src, const int* __restrict__ dst,
    const int* __restrict__ et, const int* __restrict__ offs,
    const int* __restrict__ rank, unsigned* __restrict__ ePack, int E) {
    __shared__ __align__(16) unsigned short Wt[D][D + 8];

    int bx = blockIdx.x, by = blockIdx.y;
    int tid = threadIdx.y * 64 + threadIdx.x;
    int isRel = 0, jp;
    if (bx >= nodeBlocks) {
        if (by == 1) {  // scatter range: pure (no atomics)
            int e = (bx - nodeBlocks) * 512 + tid;
            if (e < E) {
                int d = dst[e];
                ePack[offs[d] + rank[e]] = (unsigned)src[e] | ((unsigned)et[e] << 20);
            }
            return;
        }
        if (by != 0 || bx - nodeBlocks >= (R + 127) / 128) return;
        isRel = 1;
        jp = 3;
    } else {
        jp = by;
    }

    int f32 = *flag;
    int rows = isRel ? R : N;
    int row0 = (isRel ? bx - nodeBlocks : bx) * 128;
    const void* A = isRel ? rel : node;

    int lane = threadIdx.x, wv = threadIdx.y;  // wv in [0,8)
    int l16 = lane & 15, quad = lane >> 4;
    int ar = row0 + wv * 16 + l16;
    int ar_c = ar < rows ? ar : rows - 1;

    int qIdx, tIdx;
    unsigned* O = nullptr;
    switch (jp) {
        case 0: qIdx = 0; tIdx = 1; O = nodeST; break;
        case 1: qIdx = 2; tIdx = 3; O = nodeDT; break;
        case 2: qIdx = 4; tIdx = 5; break;  // loopW/evoW pair
        default: qIdx = 6; tIdx = 7; O = relRT; break;
    }

    bf16x8 af[4];
#pragma unroll
    for (int kk = 0; kk < 4; kk++) {
        int k = kk * 32 + quad * 8;
        if (f32) {
            const float* Af = (const float*)A + (size_t)ar_c * D + k;
#pragma unroll
            for (int j = 0; j < 8; j++) af[kk][j] = (short)f2bf_bits(Af[j]);
        } else {
            af[kk] = *(const bf16x8*)((const unsigned short*)A + (size_t)ar_c * D + k);
        }
    }

    const unsigned short* gQ = wT + (size_t)qIdx * D * D;
    const unsigned short* gT = wT + (size_t)tIdx * D * D;

    bf16x8 wreg[4], wreg2[4];
#pragma unroll
    for (int i = 0; i < 4; i++) {
        int c = tid + i * 512;
        wreg[i] = *(const bf16x8*)(gQ + (c >> 4) * 128 + (c & 15) * 8);
    }

    f32x4 accQ[8], accT[8];
#pragma unroll
    for (int i = 0; i < 8; i++) {
        accQ[i] = (f32x4){0.f, 0.f, 0.f, 0.f};
        accT[i] = (f32x4){0.f, 0.f, 0.f, 0.f};
    }

    for (int pass = 0; pass < 2; pass++) {
#pragma unroll
        for (int i = 0; i < 4; i++) {
            int c = tid + i * 512;
            *(bf16x8*)(&Wt[c >> 4][(c & 15) * 8]) = wreg[i];
        }
        if (pass == 0) {
#pragma unroll
            for (int i = 0; i < 4; i++) {
                int c = tid + i * 512;
                wreg2[i] = *(const bf16x8*)(gT + (c >> 4) * 128 + (c & 15) * 8);
            }
        }
        __syncthreads();
        f32x4* acc = pass ? accT : accQ;
#pragma unroll
        for (int kk = 0; kk < 4; kk++) {
#pragma unroll
            for (int nt = 0; nt < 8; nt++) {
                bf16x8 bfr = *(const bf16x8*)(&Wt[nt * 16 + l16][kk * 32 + quad * 8]);
                acc[nt] = __builtin_amdgcn_mfma_f32_16x16x32_bf16(af[kk], bfr, acc[nt], 0, 0, 0);
            }
        }
        __syncthreads();
#pragma unroll
        for (int i = 0; i < 4; i++) wreg[i] = wreg2[i];
    }

    int cr0 = row0 + wv * 16 + quad * 4;
    int odd = l16 & 1;
    if (jp != 2) {
#pragma unroll
        for (int r = 0; r < 4; r++) {
            int cr = cr0 + r;
#pragma unroll
            for (int nt = 0; nt < 8; nt++) {
                float vQ = accQ[nt][r] * LOG2E;  // pre-scale logits for exp2
                float vT = accT[nt][r];
                float oQ = __shfl_xor(vQ, 1);
                float oT = __shfl_xor(vT, 1);
                unsigned w;
                if (!odd) w = (unsigned)f2bf_bits(vQ) | ((unsigned)f2bf_bits(oQ) << 16);
                else      w = (unsigned)f2bf_bits(oT) | ((unsigned)f2bf_bits(vT) << 16);
                if (cr < rows) O[(size_t)cr * 128 + nt * 16 + l16] = w;
            }
        }
    } else {
#pragma unroll
        for (int r = 0; r < 4; r++) {
            int cr = cr0 + r;
            int deg = (cr < rows) ? cnt[cr] : 0;
#pragma unroll
            for (int nt = 0; nt < 8; nt++) {
                float vL = accQ[nt][r], vE = accT[nt][r];
                float oL = __shfl_xor(vL, 1);
                float oE = __shfl_xor(vE, 1);
                unsigned wl, we;
                if (!odd) {
                    wl = (unsigned)f2bf_bits(vL) | ((unsigned)f2bf_bits(oL) << 16);
                    we = (unsigned)f2bf_bits(vE) | ((unsigned)f2bf_bits(oE) << 16);
                } else {
                    wl = (unsigned)f2bf_bits(oL) | ((unsigned)f2bf_bits(vL) << 16);
                    we = (unsigned)f2bf_bits(oE) | ((unsigned)f2bf_bits(vE) << 16);
                }
                if (cr < rows && !odd)
                    loopSel[(size_t)cr * 64 + nt * 8 + (l16 >> 1)] = (deg > 0) ? wl : we;
            }
        }
    }
}

// ---- K5: wave-per-node aggregation + layernorm.
// 8-edge batches: 16 gathers in flight per wave before any math (latency
// hiding for L2-miss-bound gathers). Masked tail batch.
__global__ __launch_bounds__(256, 4) void agg_kernel(
    const int* __restrict__ offs, const unsigned* __restrict__ ePack,
    const uint2* __restrict__ ST, const uint2* __restrict__ RT,
    const uint2* __restrict__ DT, const unsigned* __restrict__ loopSel,
    const void* __restrict__ normv, void* __restrict__ out,
    const int* __restrict__ flag, int N) {
    int n = blockIdx.x * 4 + threadIdx.y;
    if (n >= N) return;
    int f32 = *flag;
    int lane = threadIdx.x;
    int start = offs[n], end = offs[n + 1];
    int deg = end - start;

    unsigned ul = loopSel[(unsigned)n * 64u + lane];
    uint2 ud = DT[(unsigned)n * 64u + lane];
    float qd0, qd1, td0, td1, acc0, acc1;
    unpk(ud.x, qd0, qd1);
    unpk(ud.y, td0, td1);
    unpk(ul, acc0, acc1);

    float den0 = 0.f, den1 = 0.f, h0 = 0.f, h1 = 0.f;
#define EMATH(US, UR, MSK)                                            \
    {                                                                 \
        float qs0, qs1, qr0, qr1, ts0, ts1, tr0, tr1;                 \
        unpk(US.x, qs0, qs1); unpk(UR.x, qr0, qr1);                   \
        unpk(US.y, ts0, ts1); unpk(UR.y, tr0, tr1);                   \
        float q0 = qs0 + qr0 + qd0, q1 = qs1 + qr1 + qd1;             \
        float a0 = fmaxf(q0, 0.01f * q0);                             \
        float a1 = fmaxf(q1, 0.01f * q1);                             \
        float ex0 = exp2f(a0) * (MSK), ex1 = exp2f(a1) * (MSK);       \
        den0 += ex0; den1 += ex1;                                     \
        h0 += ex0 * (ts0 + tr0);                                      \
        h1 += ex1 * (ts1 + tr1);                                      \
    }
    int e = start;
    for (; e + 7 < end; e += 8) {
        uint2 us[8], ur[8];
#pragma unroll
        for (int j = 0; j < 8; j++) {
            unsigned pk = ePack[e + j];
            us[j] = ST[((pk & 0xFFFFFu) << 6) | (unsigned)lane];
            ur[j] = RT[((pk >> 20) << 6) | (unsigned)lane];
        }
#pragma unroll
        for (int j = 0; j < 8; j++) EMATH(us[j], ur[j], 1.0f)
    }
    if (e < end) {  // masked tail batch (1-7 real edges), gathers still wide
        uint2 us[8], ur[8];
        float mk[8];
#pragma unroll
        for (int j = 0; j < 8; j++) {
            int ej = e + j < end ? e + j : end - 1;
            mk[j] = (e + j < end) ? 1.0f : 0.0f;
            unsigned pk = ePack[ej];
            us[j] = ST[((pk & 0xFFFFFu) << 6) | (unsigned)lane];
            ur[j] = RT[((pk >> 20) << 6) | (unsigned)lane];
        }
#pragma unroll
        for (int j = 0; j < 8; j++) EMATH(us[j], ur[j], mk[j])
    }

    float x0, x1;
    if (deg > 0) {
        float nrm = ldf(normv, n, f32);
        x0 = (h0 / den0 + td0) * nrm + acc0;  // td folded: h = h' + td*den
        x1 = (h1 / den1 + td1) * nrm + acc1;
    } else {
        x0 = acc0;
        x1 = acc1;
    }

    float s = x0 + x1, ss = x0 * x0 + x1 * x1;
#pragma unroll
    for (int o = 32; o; o >>= 1) {
        s += __shfl_xor(s, o);
        ss += __shfl_xor(ss, o);
    }
    float mu = s * (1.f / 128.f);
    float var = ss * (1.f / 128.f) - mu * mu;
    float rstd = rsqrtf(var + 1e-5f);
    float y0 = (x0 - mu) * rstd, y1 = (x1 - mu) * rstd;

    if (f32) {
        ((float2*)out)[(unsigned)n * 64u + lane] = make_float2(y0, y1);
    } else {
        unsigned ob = (unsigned)f2bf_bits(y0) | ((unsigned)f2bf_bits(y1) << 16);
        ((unsigned*)out)[(unsigned)n * 64u + lane] = ob;
    }
}

extern "C" void kernel_launch(void* const* d_in, const int* in_sizes, int n_in,
                              void* d_out, int out_size, void* d_ws, size_t ws_size,
                              hipStream_t stream) {
    const void* node = d_in[0];
    const void* rel = d_in[1];
    const void* normv = d_in[2];
    const void* wtrip = d_in[3];
    const void* wquad = d_in[4];
    const void* loopW = d_in[5];
    const void* evoW = d_in[6];
    const int* src = (const int*)d_in[7];
    const int* dst = (const int*)d_in[8];
    const int* et = (const int*)d_in[9];

    int N = in_sizes[0] / D;
    int R = in_sizes[1] / D;
    int E = in_sizes[7];
    int nb = (N + 255) / 256;
    int nodeBlocks = (N + 127) / 128;
    int relBlocks = (R + 127) / 128;
    int scatBlocks = (E + 511) / 512;

    char* p = (char*)d_ws;
    auto alloc = [&](size_t bytes) -> void* {
        void* r = (void*)p;
        p += (bytes + 255) & ~(size_t)255;
        return r;
    };
    unsigned* nodeST = (unsigned*)alloc((size_t)N * 128 * 4);
    unsigned* nodeDT = (unsigned*)alloc((size_t)N * 128 * 4);
    unsigned* relRT = (unsigned*)alloc((size_t)R * 128 * 4);
    unsigned* loopSel = (unsigned*)alloc((size_t)N * 64 * 4);
    unsigned short* wT = (unsigned short*)alloc((size_t)8 * D * D * 2);
    int* cnt = (int*)alloc((size_t)N * 4);
    int* offs = (int*)alloc((size_t)(N + 1) * 4);
    int* part = (int*)alloc((size_t)(nb + 1) * 4);
    int* rank = (int*)alloc((size_t)E * 4);
    unsigned* ePack = (unsigned*)alloc((size_t)E * 4);
    int* flag = (int*)alloc(4);

    hipMemsetAsync(cnt, 0, (size_t)N * 4, stream);
    prep_kernel<<<272 + (E + 255) / 256, 256, 0, stream>>>(
        node, wtrip, wquad, loopW, evoW, wT, cnt, rank, dst, flag, E);
    scan_block<<<nb, 256, 0, stream>>>(cnt, offs, part, N);
    scan_fix<<<nb, 256, 0, stream>>>(offs, part, N, E);
    int xext = nodeBlocks + (scatBlocks > relBlocks ? scatBlocks : relBlocks);
    gemm_kernel<<<dim3(xext, 3), dim3(64, 8), 0, stream>>>(
        node, rel, wT, cnt, nodeST, nodeDT, relRT, loopSel, flag, N, R, nodeBlocks,
        src, dst, et, offs, rank, ePack, E);
    agg_kernel<<<(N + 3) / 4, dim3(64, 4), 0, stream>>>(
        offs, ePack, (const uint2*)nodeST, (const uint2*)relRT, (const uint2*)nodeDT,
        loopSel, normv, d_out, flag, N);
}